// Round 20
// baseline (428.736 us; speedup 1.0000x reference)
//
#include <hip/hip_runtime.h>

#define CIN_B 512
#define CIN_F0 40
#define CIN_D 32
#define CIN_S 200

typedef _Float16 f16x8 __attribute__((ext_vector_type(8)));
typedef _Float16 f16x2 __attribute__((ext_vector_type(2)));
typedef float floatx16 __attribute__((ext_vector_type(16)));

__device__ __forceinline__ unsigned short f2h(float f) {
    _Float16 h = (_Float16)f;           // RNE
    return *(unsigned short*)&h;
}
__device__ __forceinline__ float h2f(unsigned short u) {
    return (float)(*(_Float16*)&u);
}
// elementwise f16 add of 8 packed halves
__device__ __forceinline__ uint4 add8h(uint4 a, uint4 b) {
    union { uint4 v; _Float16 h[8]; } x, y, r;
    x.v = a; y.v = b;
#pragma unroll
    for (int q = 0; q < 8; ++q) r.h[q] = x.h[q] + y.h[q];
    return r.v;
}
// v * broadcast-pair(s2): 4 v_pk_mul_f16 sharing one packed scale reg
__device__ __forceinline__ f16x8 mulbc(f16x8 v, unsigned int s2) {
    union { unsigned int u; f16x2 p; } sc; sc.u = s2;
    union { f16x8 h; f16x2 p[4]; } a, r;
    a.h = v;
#pragma unroll
    for (int q = 0; q < 4; ++q) r.p[q] = a.p[q] * sc.p;
    return r.h;
}

// Wtk[kc][nn][kw] = f16(W[(i*FI + kk*16+kw)*200 + nn]); kc=i*KCPI+kk.
// kk==HALVE rows stored 0.5x (read by both overlap slices; 0.5x+0.5x==x exact).
template <int FI, int KCPI, int HALVE>
__global__ __launch_bounds__(256) void prep_w(const float* __restrict__ W,
                                              unsigned short* __restrict__ Wtk) {
    const int kc = blockIdx.x;
    const int nn = threadIdx.x;
    const int i = kc / KCPI;
    const int kk = kc - i * KCPI;
    const float sc = (kk == HALVE) ? 0.5f : 1.0f;
    unsigned short v[16];
#pragma unroll
    for (int kw = 0; kw < 16; ++kw) {
        int j = kk * 16 + kw;
        float f = 0.f;
        if (j < FI && nn < CIN_S) f = sc * W[(size_t)(i * FI + j) * CIN_S + nn];
        v[kw] = f2h(f);
    }
    uint4* dst = (uint4*)(Wtk + ((size_t)kc * 256 + nn) * 16);
    dst[0] = ((const uint4*)v)[0];
    dst[1] = ((const uint4*)v)[1];
}

// fused for the two big weight matrices; kc = i*13+kk, kk==6 stored 0.5x.
__global__ __launch_bounds__(256) void prep_w2(const float* __restrict__ Wa,
                                               unsigned short* __restrict__ Wta,
                                               const float* __restrict__ Wb,
                                               unsigned short* __restrict__ Wtb) {
    const int half = blockIdx.x >= 520;
    const int kc = half ? blockIdx.x - 520 : blockIdx.x;
    const float* W = half ? Wb : Wa;
    unsigned short* Wtk = half ? Wtb : Wta;
    const int nn = threadIdx.x;
    const int i = kc / 13;
    const int kk = kc - i * 13;
    const float sc = (kk == 6) ? 0.5f : 1.0f;
    unsigned short v[16];
#pragma unroll
    for (int kw = 0; kw < 16; ++kw) {
        int j = kk * 16 + kw;
        float f = 0.f;
        if (j < CIN_S && nn < CIN_S) f = sc * W[(size_t)(i * CIN_S + j) * CIN_S + nn];
        v[kw] = f2h(f);
    }
    uint4* dst = (uint4*)(Wtk + ((size_t)kc * 256 + nn) * 16);
    dst[0] = ((const uint4*)v)[0];
    dst[1] = ((const uint4*)v)[1];
}

// X0hd[b][d][i(pad 48)] = f16(x0[b][i][d]);  Xh[b][i][d] = f16(x0[b][i][d])
__global__ __launch_bounds__(256) void prep_x(const float* __restrict__ X,
                                              unsigned short* __restrict__ X0hd,
                                              unsigned short* __restrict__ Xh) {
    int e = blockIdx.x * 256 + threadIdx.x;   // 512*40*32
    int d = e & 31;
    int rest = e >> 5;
    int i = rest % CIN_F0;
    int b = rest / CIN_F0;
    unsigned short v = f2h(X[e]);
    Xh[e] = v;
    X0hd[((size_t)b * CIN_D + d) * 48 + i] = v;
    if (e < CIN_B * CIN_D * 8) {     // zero pads i=40..47
        int q = e & 7, dd = (e >> 3) & 31, bb = e >> 8;
        X0hd[((size_t)bb * CIN_D + dd) * 48 + 40 + q] = 0;
    }
}

// ---- layer 1 (R19-proven, 2 b / 7 waves / jh 2-split) ----------------------
// Writes H1p[jh][b][d][n](224) + outp1[jh] d-sum partials.
// mfma_f32_32x32x16_f16: A[m=lane&31][k=(lane>>5)*8+e]; B[k][col=lane&31];
// C/D col=lane&31, row=(reg&3)+8*(reg>>2)+4*(lane>>5).
__global__ __launch_bounds__(448, 4)
void cin_layer1(const unsigned short* __restrict__ Hsrc,
                const unsigned short* __restrict__ Xh,
                const unsigned short* __restrict__ Wtk,
                unsigned short* __restrict__ Hout,
                float* __restrict__ outp) {
    constexpr int NKC = 2, KT = 3, JROW = 48;
    __shared__ __align__(16) unsigned short Bp[2 * NKC * 512];
    __shared__ unsigned int Xl[CIN_F0 * CIN_D];

    const int tid = threadIdx.x;
    const int b0 = blockIdx.x * 2;
    const int jh = blockIdx.y;
    const int kks = jh;                       // KSTEP=1, kc {0,1}/{1,2}

    for (int e = tid; e < CIN_F0 * CIN_D; e += 448) {
        unsigned int lo = Xh[(size_t)b0 * 1280 + e];
        unsigned int hi = Xh[(size_t)(b0 + 1) * 1280 + e];
        Xl[e] = lo | (hi << 16);
    }
    {
        const int j0 = kks * 16;
        uint4* Bpu = (uint4*)Bp;
        for (int g = tid; g < 2 * 64 * NKC; g += 448) {
            int bb = g / (64 * NKC), r = g - bb * (64 * NKC);
            int d = r / (2 * NKC), c = r - d * (2 * NKC);
            uint4 v = ((const uint4*)Hsrc)[(((size_t)(b0 + bb) * CIN_D + d) * JROW + j0) / 8 + c];
            Bpu[(bb * NKC + (c >> 1)) * 64 + (c & 1) * 32 + d] = v;
        }
    }
    __syncthreads();

    const int wave = tid >> 6, lane = tid & 63;
    const int l32 = lane & 31, hl = lane >> 5;
    const int tile = wave;

    const unsigned short* Abase =
        Wtk + ((size_t)(tile * 32 + l32) * 16 + hl * 8) + (size_t)kks * 4096;

    floatx16 acc0, acc1;
#pragma unroll
    for (int r = 0; r < 16; ++r) { acc0[r] = 0.f; acc1[r] = 0.f; }

#pragma unroll 1
    for (int i2 = 0; i2 < CIN_F0; i2 += 2) {
        const unsigned int xpa = Xl[i2 * CIN_D + l32];
        const unsigned int xpb = Xl[(i2 + 1) * CIN_D + l32];
        const unsigned int lo2a = (xpa & 0xffffu) | (xpa << 16);
        const unsigned int hi2a = (xpa >> 16) | (xpa & 0xffff0000u);
        const unsigned int lo2b = (xpb & 0xffffu) | (xpb << 16);
        const unsigned int hi2b = (xpb >> 16) | (xpb & 0xffff0000u);
        const unsigned short* Aia = Abase + (size_t)i2 * (KT * 4096);
        const unsigned short* Aib = Aia + (size_t)(KT * 4096);
#pragma unroll
        for (int kk = 0; kk < NKC; ++kk) {
            const f16x8 Afa = *(const f16x8*)(Aia + kk * 4096);
            const f16x8 Afb = *(const f16x8*)(Aib + kk * 4096);
            const f16x8 B0 = *(const f16x8*)&Bp[(0 * NKC + kk) * 512 + lane * 8];
            const f16x8 B1 = *(const f16x8*)&Bp[(1 * NKC + kk) * 512 + lane * 8];
            acc0 = __builtin_amdgcn_mfma_f32_32x32x16_f16(Afa, mulbc(B0, lo2a), acc0, 0, 0, 0);
            acc1 = __builtin_amdgcn_mfma_f32_32x32x16_f16(Afa, mulbc(B1, hi2a), acc1, 0, 0, 0);
            acc0 = __builtin_amdgcn_mfma_f32_32x32x16_f16(Afb, mulbc(B0, lo2b), acc0, 0, 0, 0);
            acc1 = __builtin_amdgcn_mfma_f32_32x32x16_f16(Afb, mulbc(B1, hi2b), acc1, 0, 0, 0);
        }
    }

#pragma unroll
    for (int bb = 0; bb < 2; ++bb) {
        const floatx16& a = bb ? acc1 : acc0;
        unsigned short* dst = Hout + (size_t)jh * ((size_t)CIN_B * CIN_D * 224) +
                              ((size_t)(b0 + bb) * CIN_D + l32) * 224 + tile * 32;
#pragma unroll
        for (int qd = 0; qd < 4; ++qd) {
            ushort4 pk;
            pk.x = f2h(a[4 * qd + 0]);
            pk.y = f2h(a[4 * qd + 1]);
            pk.z = f2h(a[4 * qd + 2]);
            pk.w = f2h(a[4 * qd + 3]);
            *(ushort4*)&dst[8 * qd + 4 * hl] = pk;
        }
#pragma unroll
        for (int r = 0; r < 16; ++r) {
            float v = a[r];
            v += __shfl_xor(v, 1);
            v += __shfl_xor(v, 2);
            v += __shfl_xor(v, 4);
            v += __shfl_xor(v, 8);
            v += __shfl_xor(v, 16);
            if (l32 == 0) {
                int n = tile * 32 + (r & 3) + 8 * (r >> 2) + 4 * hl;
                if (n < CIN_S)
                    outp[((size_t)jh * CIN_B + b0 + bb) * CIN_S + n] = v;
            }
        }
    }
}

// ---- big layers: 4 b per block, 256 thr / 4 waves, jh 2-split --------------
// Each A-fragment pair feeds 8 MFMAs (4 b x 2 i) -> 2x compute per A-stall
// vs R19 (the measured bottleneck: ~200cyc L2 latency per 128cyc of MFMA).
// Input Hsrc = 2 partials [p][b][d][224] (summed f16 during staging).
// MODE 2: writes H2p[jh][b][d][n](224) partials + outp. MODE 3: outp only.
template <int MODE>
__global__ __launch_bounds__(256, 4)
void cin_layer4(const unsigned short* __restrict__ Hsrc,
                const unsigned short* __restrict__ Xh,
                const unsigned short* __restrict__ Wtk,
                unsigned short* __restrict__ Hout,
                float* __restrict__ outp) {
    constexpr int NKC = 7, KT = 13, KSTEP = 6;
    __shared__ __align__(16) unsigned short Bp[4 * NKC * 512];  // 28 KB
    __shared__ unsigned int Xl[2][CIN_F0 * CIN_D];              // 10 KB

    const int tid = threadIdx.x;
    const int b0 = blockIdx.x * 4;
    const int jh = blockIdx.y;
    const int th = blockIdx.z;
    const int kks = jh * KSTEP;

    // stage packed x-pairs for pairs (b0,b0+1) and (b0+2,b0+3)
    for (int e = tid; e < 2 * CIN_F0 * CIN_D; e += 256) {
        int p = e / 1280, r = e - p * 1280;
        unsigned int lo = Xh[(size_t)(b0 + 2 * p) * 1280 + r];
        unsigned int hi = Xh[(size_t)(b0 + 2 * p + 1) * 1280 + r];
        Xl[p][r] = lo | (hi << 16);
    }
    // stage B-frags (4 b, fragment order), summing the 2 input partials
    {
        const int j0 = kks * 16;
        constexpr size_t POFF = (size_t)CIN_B * CIN_D * 224 / 8;  // uint4 units
        uint4* Bpu = (uint4*)Bp;
        for (int g = tid; g < 4 * 64 * NKC; g += 256) {
            int bb = g / (64 * NKC), r = g - bb * (64 * NKC);
            int d = r / (2 * NKC), c = r - d * (2 * NKC);
            size_t idx = (((size_t)(b0 + bb) * CIN_D + d) * 224 + j0) / 8 + c;
            uint4 v = add8h(((const uint4*)Hsrc)[idx],
                            ((const uint4*)Hsrc)[idx + POFF]);
            Bpu[(bb * NKC + (c >> 1)) * 64 + (c & 1) * 32 + d] = v;
        }
    }
    __syncthreads();

    const int wave = tid >> 6, lane = tid & 63;
    const int tile = th * 4 + wave;          // 0..7
    if (tile >= 7) return;                   // tile 7: zero-pad rows
    const int l32 = lane & 31, hl = lane >> 5;

    const unsigned short* Abase =
        Wtk + ((size_t)(tile * 32 + l32) * 16 + hl * 8) + (size_t)kks * 4096;

    floatx16 acc[4];
#pragma unroll
    for (int bb = 0; bb < 4; ++bb)
#pragma unroll
        for (int r = 0; r < 16; ++r) acc[bb][r] = 0.f;

#pragma unroll 1
    for (int i2 = 0; i2 < CIN_F0; i2 += 2) {
        const unsigned int x0a = Xl[0][i2 * CIN_D + l32];
        const unsigned int x0b = Xl[0][(i2 + 1) * CIN_D + l32];
        const unsigned int x1a = Xl[1][i2 * CIN_D + l32];
        const unsigned int x1b = Xl[1][(i2 + 1) * CIN_D + l32];
        const unsigned int s0a = (x0a & 0xffffu) | (x0a << 16);
        const unsigned int s1a = (x0a >> 16) | (x0a & 0xffff0000u);
        const unsigned int s0b = (x0b & 0xffffu) | (x0b << 16);
        const unsigned int s1b = (x0b >> 16) | (x0b & 0xffff0000u);
        const unsigned int s2a = (x1a & 0xffffu) | (x1a << 16);
        const unsigned int s3a = (x1a >> 16) | (x1a & 0xffff0000u);
        const unsigned int s2b = (x1b & 0xffffu) | (x1b << 16);
        const unsigned int s3b = (x1b >> 16) | (x1b & 0xffff0000u);
        const unsigned short* Aia = Abase + (size_t)i2 * (KT * 4096);
        const unsigned short* Aib = Aia + (size_t)(KT * 4096);
#pragma unroll
        for (int kk = 0; kk < NKC; ++kk) {
            const f16x8 Afa = *(const f16x8*)(Aia + kk * 4096);
            const f16x8 Afb = *(const f16x8*)(Aib + kk * 4096);
            const f16x8 B0 = *(const f16x8*)&Bp[(0 * NKC + kk) * 512 + lane * 8];
            const f16x8 B1 = *(const f16x8*)&Bp[(1 * NKC + kk) * 512 + lane * 8];
            const f16x8 B2 = *(const f16x8*)&Bp[(2 * NKC + kk) * 512 + lane * 8];
            const f16x8 B3 = *(const f16x8*)&Bp[(3 * NKC + kk) * 512 + lane * 8];
            acc[0] = __builtin_amdgcn_mfma_f32_32x32x16_f16(Afa, mulbc(B0, s0a), acc[0], 0, 0, 0);
            acc[1] = __builtin_amdgcn_mfma_f32_32x32x16_f16(Afa, mulbc(B1, s1a), acc[1], 0, 0, 0);
            acc[2] = __builtin_amdgcn_mfma_f32_32x32x16_f16(Afa, mulbc(B2, s2a), acc[2], 0, 0, 0);
            acc[3] = __builtin_amdgcn_mfma_f32_32x32x16_f16(Afa, mulbc(B3, s3a), acc[3], 0, 0, 0);
            acc[0] = __builtin_amdgcn_mfma_f32_32x32x16_f16(Afb, mulbc(B0, s0b), acc[0], 0, 0, 0);
            acc[1] = __builtin_amdgcn_mfma_f32_32x32x16_f16(Afb, mulbc(B1, s1b), acc[1], 0, 0, 0);
            acc[2] = __builtin_amdgcn_mfma_f32_32x32x16_f16(Afb, mulbc(B2, s2b), acc[2], 0, 0, 0);
            acc[3] = __builtin_amdgcn_mfma_f32_32x32x16_f16(Afb, mulbc(B3, s3b), acc[3], 0, 0, 0);
        }
    }

    // ---- epilogue ----
#pragma unroll
    for (int bb = 0; bb < 4; ++bb) {
        const floatx16& a = acc[bb];
        if constexpr (MODE == 2) {   // H2p[jh][b][d][n] f16 partials
            unsigned short* dst = Hout + (size_t)jh * ((size_t)CIN_B * CIN_D * 224) +
                                  ((size_t)(b0 + bb) * CIN_D + l32) * 224 + tile * 32;
#pragma unroll
            for (int qd = 0; qd < 4; ++qd) {
                ushort4 pk;
                pk.x = f2h(a[4 * qd + 0]);
                pk.y = f2h(a[4 * qd + 1]);
                pk.z = f2h(a[4 * qd + 2]);
                pk.w = f2h(a[4 * qd + 3]);
                *(ushort4*)&dst[8 * qd + 4 * hl] = pk;
            }
        }
        // d-sum over col = l32 (fp32), K-slice partial
#pragma unroll
        for (int r = 0; r < 16; ++r) {
            float v = a[r];
            v += __shfl_xor(v, 1);
            v += __shfl_xor(v, 2);
            v += __shfl_xor(v, 4);
            v += __shfl_xor(v, 8);
            v += __shfl_xor(v, 16);
            if (l32 == 0) {
                int n = tile * 32 + (r & 3) + 8 * (r >> 2) + 4 * hl;
                if (n < CIN_S)
                    outp[((size_t)jh * CIN_B + b0 + bb) * CIN_S + n] = v;
            }
        }
    }
}

// out[b, t] for t in [0,600): sums the 2 K-slice partials of each layer
__global__ __launch_bounds__(256) void cin_outc(const float* __restrict__ p1,
                                                const float* __restrict__ p2,
                                                const float* __restrict__ p3,
                                                float* __restrict__ out) {
    int e = blockIdx.x * 256 + threadIdx.x;   // 512*600 exact
    int b = e / 600, t = e - b * 600;
    int lay = t / 200, n = t - lay * 200;
    const float* p = (lay == 0) ? p1 : ((lay == 1) ? p2 : p3);
    out[e] = p[(size_t)b * CIN_S + n] + p[(size_t)(CIN_B + b) * CIN_S + n];
}

extern "C" void kernel_launch(void* const* d_in, const int* in_sizes, int n_in,
                              void* d_out, int out_size, void* d_ws, size_t ws_size,
                              hipStream_t stream) {
    const float* X  = (const float*)d_in[0];
    const float* W0 = (const float*)d_in[1];
    const float* W1 = (const float*)d_in[2];
    const float* W2 = (const float*)d_in[3];
    float* out = (float*)d_out;

    const size_t PS = (size_t)CIN_B * CIN_D * 224;            // H plane elems
    unsigned short* Wtk1 = (unsigned short*)d_ws;             // 120*4096
    unsigned short* Wtk2 = Wtk1 + (size_t)120 * 4096;         // 520*4096 each
    unsigned short* Wtk3 = Wtk2 + (size_t)520 * 4096;
    unsigned short* X0hd = Wtk3 + (size_t)520 * 4096;         // 512*32*48
    unsigned short* Xh   = X0hd + (size_t)CIN_B * CIN_D * 48; // 512*40*32
    unsigned short* H1p  = Xh + (size_t)CIN_B * CIN_F0 * CIN_D; // 2 * PS
    unsigned short* H2p  = H1p + 2 * PS;                      // 2 * PS
    float* outp1 = (float*)(H2p + 2 * PS);                    // 2*512*200 each
    float* outp2 = outp1 + (size_t)2 * CIN_B * CIN_S;
    float* outp3 = outp2 + (size_t)2 * CIN_B * CIN_S;
    // total ws ~44 MB

    prep_w<CIN_F0, 3, 1><<<120, 256, 0, stream>>>(W0, Wtk1);
    prep_w2<<<1040, 256, 0, stream>>>(W1, Wtk2, W2, Wtk3);
    prep_x<<<(CIN_B * CIN_F0 * CIN_D) / 256, 256, 0, stream>>>(X, X0hd, Xh);

    // layer1: K=1600, slices kc{0,1}/{1,2} (kc1 halved)
    cin_layer1<<<dim3(CIN_B / 2, 2), 448, 0, stream>>>(X0hd, Xh, Wtk1, H1p, outp1);
    // layer2: 4b blocks, slices kc{0..6}/{6..12} (kc6 halved)
    cin_layer4<2><<<dim3(CIN_B / 4, 2, 2), 256, 0, stream>>>(H1p, Xh, Wtk2, H2p, outp2);
    // layer3: same, input = H2p partials (summed in staging)
    cin_layer4<3><<<dim3(CIN_B / 4, 2, 2), 256, 0, stream>>>(H2p, Xh, Wtk3, nullptr, outp3);

    cin_outc<<<(CIN_B * 600) / 256, 256, 0, stream>>>(outp1, outp2, outp3, out);
}

// Round 21
// 271.930 us; speedup vs baseline: 1.5766x; 1.5766x over previous
//
#include <hip/hip_runtime.h>

#define CIN_B 512
#define CIN_F0 40
#define CIN_D 32
#define CIN_S 200

typedef _Float16 f16x8 __attribute__((ext_vector_type(8)));
typedef _Float16 f16x2 __attribute__((ext_vector_type(2)));
typedef float floatx16 __attribute__((ext_vector_type(16)));

__device__ __forceinline__ unsigned short f2h(float f) {
    _Float16 h = (_Float16)f;           // RNE
    return *(unsigned short*)&h;
}
__device__ __forceinline__ float h2f(unsigned short u) {
    return (float)(*(_Float16*)&u);
}
// v * broadcast(s2): 4 v_pk_mul_f16 sharing one scale register
__device__ __forceinline__ f16x8 mulbc(f16x8 v, unsigned int s2) {
    union { unsigned int u; f16x2 p; } sc; sc.u = s2;
    union { f16x8 h; f16x2 p[4]; } a, r;
    a.h = v;
#pragma unroll
    for (int q = 0; q < 4; ++q) r.p[q] = a.p[q] * sc.p;
    return r.h;
}

// Wtk[kc][nn 0..255][kw 0..15] = f16(W[(i*FI + kk*16+kw)*200 + nn]); kc=i*KCPI+kk.
template <int FI, int KCPI>
__global__ __launch_bounds__(256) void prep_w(const float* __restrict__ W,
                                              unsigned short* __restrict__ Wtk) {
    const int kc = blockIdx.x;
    const int nn = threadIdx.x;
    const int i = kc / KCPI;
    const int kk = kc - i * KCPI;
    unsigned short v[16];
#pragma unroll
    for (int kw = 0; kw < 16; ++kw) {
        int j = kk * 16 + kw;
        float f = 0.f;
        if (j < FI && nn < CIN_S) f = W[(size_t)(i * FI + j) * CIN_S + nn];
        v[kw] = f2h(f);
    }
    uint4* dst = (uint4*)(Wtk + ((size_t)kc * 256 + nn) * 16);
    dst[0] = ((const uint4*)v)[0];
    dst[1] = ((const uint4*)v)[1];
}

// fused for the two big weight matrices; kc = i*13+kk, kk==6 stored 0.5x (read
// by BOTH j-halves: 0.5x + 0.5x == x; 0.5 scaling exact in fp16).
__global__ __launch_bounds__(256) void prep_w2(const float* __restrict__ Wa,
                                               unsigned short* __restrict__ Wta,
                                               const float* __restrict__ Wb,
                                               unsigned short* __restrict__ Wtb) {
    const int half = blockIdx.x >= 520;
    const int kc = half ? blockIdx.x - 520 : blockIdx.x;
    const float* W = half ? Wb : Wa;
    unsigned short* Wtk = half ? Wtb : Wta;
    const int nn = threadIdx.x;
    const int i = kc / 13;
    const int kk = kc - i * 13;
    const float sc = (kk == 6) ? 0.5f : 1.0f;
    unsigned short v[16];
#pragma unroll
    for (int kw = 0; kw < 16; ++kw) {
        int j = kk * 16 + kw;
        float f = 0.f;
        if (j < CIN_S && nn < CIN_S) f = sc * W[(size_t)(i * CIN_S + j) * CIN_S + nn];
        v[kw] = f2h(f);
    }
    uint4* dst = (uint4*)(Wtk + ((size_t)kc * 256 + nn) * 16);
    dst[0] = ((const uint4*)v)[0];
    dst[1] = ((const uint4*)v)[1];
}

// X0hd[b][d][i(pad 48)] = f16(x0[b][i][d]);  Xh[b][i][d] = f16(x0[b][i][d])
__global__ __launch_bounds__(256) void prep_x(const float* __restrict__ X,
                                              unsigned short* __restrict__ X0hd,
                                              unsigned short* __restrict__ Xh) {
    int e = blockIdx.x * 256 + threadIdx.x;   // 512*40*32
    int d = e & 31;
    int rest = e >> 5;
    int i = rest % CIN_F0;
    int b = rest / CIN_F0;
    unsigned short v = f2h(X[e]);
    Xh[e] = v;
    X0hd[((size_t)b * CIN_D + d) * 48 + i] = v;
    if (e < CIN_B * CIN_D * 8) {     // zero pads i=40..47
        int q = e & 7, dd = (e >> 3) & 31, bb = e >> 8;
        X0hd[((size_t)bb * CIN_D + dd) * 48 + 40 + q] = 0;
    }
}

// One layer (j-half per blockIdx.y for MODE 2/3). Block = 2 b x 7 waves (448).
// Best-measured structure (R14/R16, 279.9 us total): i2-blocked kk loop (B
// read once per (i2,kk), feeds 4 MFMAs), x folded into B via v_pk_mul_f16,
// acc = MFMA C operand (32 AGPRs), rotation-register prefetch (Ar 2 ahead,
// Br 1 ahead). Structural plateau: MFMA-issue and per-CU L2-BW both predict
// ~27 us/big-layer; measured 85 us is per-wave load->mul->MFMA latency the
// compiler won't pipeline deeper (R5-R20: 15 variants triangulated).
// mfma_f32_32x32x16_f16: A[m=lane&31][k=(lane>>5)*8+e]; B[k][col=lane&31];
// C/D col=lane&31, row=(reg&3)+8*(reg>>2)+4*(lane>>5).
template <int NKC, int KCPI_TOT, int JROW, int MODE>
__global__ __launch_bounds__(448, 4)
void cin_layer(const unsigned short* __restrict__ Hsrc,
               const unsigned short* __restrict__ Xh,
               const unsigned short* __restrict__ Wtk,
               unsigned short* __restrict__ Hout,
               float* __restrict__ outp) {
    __shared__ __align__(16) unsigned short Bp[2 * NKC * 512];   // 6 / 14 KB
    __shared__ unsigned int Xl[CIN_F0 * CIN_D];                  // 5 KB

    const int tid = threadIdx.x;
    const int b0 = blockIdx.x * 2;
    const int jh = (MODE == 1) ? 0 : blockIdx.y;
    const int kks = jh * 6;

    // stage packed x-pairs: Xl[i*32+d] = x[b0][i][d] | x[b0+1][i][d]<<16
    for (int e = tid; e < CIN_F0 * CIN_D; e += 448) {
        unsigned int lo = Xh[(size_t)b0 * (CIN_F0 * CIN_D) + e];
        unsigned int hi = Xh[(size_t)(b0 + 1) * (CIN_F0 * CIN_D) + e];
        Xl[e] = lo | (hi << 16);
    }
    // stage B-frags into LDS (fragment order, i-invariant) — R10/R13 layout
    {
        const int j0 = (MODE == 1) ? 0 : jh * 96;
        uint4* Bpu = (uint4*)Bp;
        for (int g = tid; g < 2 * 64 * NKC; g += 448) {
            int bb = g / (64 * NKC), r = g - bb * (64 * NKC);
            int d = r / (2 * NKC), c = r - d * (2 * NKC);
            uint4 v = ((const uint4*)Hsrc)[(((size_t)(b0 + bb) * CIN_D + d) * JROW + j0) / 8 + c];
            Bpu[(bb * NKC + (c >> 1)) * 64 + (c & 1) * 32 + d] = v;
        }
    }
    __syncthreads();

    const int wave = tid >> 6, lane = tid & 63;
    const int l32 = lane & 31, hl = lane >> 5;
    const int tile = wave;

    const int aB = (tile * 32 + l32) * 16 + hl * 8;   // per-lane element offset
    constexpr int NS = 20 * NKC;

    f16x8 Ar[2][2];   // [slot][0: i=iA, 1: i=iA+1]
    f16x8 Br[2][2];   // [slot][b-index]

    auto ldA = [&](int s, int slot) {
        int ss = (s < NS) ? s : (NS - 1);
        int iA = 2 * (ss / NKC), kk = ss % NKC;
        int e = (iA * KCPI_TOT + kks + kk) * 4096 + aB;
        Ar[slot][0] = *(const f16x8*)(Wtk + e);
        Ar[slot][1] = *(const f16x8*)(Wtk + e + KCPI_TOT * 4096);
    };
    auto ldB = [&](int s, int slot) {
        int ss = (s < NS) ? s : (NS - 1);
        int kk = ss % NKC;
        Br[slot][0] = *(const f16x8*)&Bp[(0 * NKC + kk) * 512 + lane * 8];
        Br[slot][1] = *(const f16x8*)&Bp[(1 * NKC + kk) * 512 + lane * 8];
    };

    ldA(0, 0);
    ldA(1, 1);
    ldB(0, 0);

    floatx16 acc0, acc1;
#pragma unroll
    for (int r = 0; r < 16; ++r) { acc0[r] = 0.f; acc1[r] = 0.f; }
    unsigned int xs0a = 0, xs1a = 0, xs0b = 0, xs1b = 0;

#pragma unroll 1
    for (int s0 = 0; s0 < NS; s0 += 2 * NKC) {
#pragma unroll
        for (int t = 0; t < 2 * NKC; ++t) {
            const int s = s0 + t;
            const int kk = t % NKC;                   // literal
            if (kk == 0) {                            // xs update (2x per body)
                const int iA = (s0 / NKC + (t ? 1 : 0)) * 2;
                unsigned int xpa = Xl[iA * CIN_D + l32];
                unsigned int xpb = Xl[(iA + 1) * CIN_D + l32];
                xs0a = (xpa & 0xffffu) | (xpa << 16);
                xs1a = (xpa >> 16) | (xpa & 0xffff0000u);
                xs0b = (xpb & 0xffffu) | (xpb << 16);
                xs1b = (xpb >> 16) | (xpb & 0xffff0000u);
            }
            ldB(s + 1, (t + 1) & 1);                  // B prefetch, 1 ahead
            const int sl = t & 1;
            acc0 = __builtin_amdgcn_mfma_f32_32x32x16_f16(
                Ar[sl][0], mulbc(Br[sl][0], xs0a), acc0, 0, 0, 0);
            acc1 = __builtin_amdgcn_mfma_f32_32x32x16_f16(
                Ar[sl][0], mulbc(Br[sl][1], xs1a), acc1, 0, 0, 0);
            acc0 = __builtin_amdgcn_mfma_f32_32x32x16_f16(
                Ar[sl][1], mulbc(Br[sl][0], xs0b), acc0, 0, 0, 0);
            acc1 = __builtin_amdgcn_mfma_f32_32x32x16_f16(
                Ar[sl][1], mulbc(Br[sl][1], xs1b), acc1, 0, 0, 0);
            ldA(s + 2, sl);                           // A prefetch, 2 ahead
        }
    }

    // ---- epilogue ----
#pragma unroll
    for (int bb = 0; bb < 2; ++bb) {
        const floatx16& a = bb ? acc1 : acc0;

        if constexpr (MODE == 1) {   // H1[b][d][n] f16, n-tile of 32
            unsigned short* dst =
                Hout + ((size_t)(b0 + bb) * CIN_D + l32) * 224 + tile * 32;
#pragma unroll
            for (int qd = 0; qd < 4; ++qd) {
                ushort4 pk;
                pk.x = f2h(a[4 * qd + 0]);
                pk.y = f2h(a[4 * qd + 1]);
                pk.z = f2h(a[4 * qd + 2]);
                pk.w = f2h(a[4 * qd + 3]);
                *(ushort4*)&dst[8 * qd + 4 * hl] = pk;
            }
        }
        if constexpr (MODE == 2) {   // Hacc[jh][b][n][d] f16 partials
            unsigned short* hb2 =
                Hout + (((size_t)jh * CIN_B + b0 + bb) * 208) * CIN_D + l32;
#pragma unroll
            for (int r = 0; r < 16; ++r) {
                int n = tile * 32 + (r & 3) + 8 * (r >> 2) + 4 * hl;
                if (n < 208) hb2[(size_t)n * CIN_D] = f2h(a[r]);
            }
        }

        // d-sum over col = l32 (fp32)
#pragma unroll
        for (int r = 0; r < 16; ++r) {
            float v = a[r];
            v += __shfl_xor(v, 1);
            v += __shfl_xor(v, 2);
            v += __shfl_xor(v, 4);
            v += __shfl_xor(v, 8);
            v += __shfl_xor(v, 16);
            if (l32 == 0) {
                int n = tile * 32 + (r & 3) + 8 * (r >> 2) + 4 * hl;
                if (n < CIN_S) {
                    if constexpr (MODE == 1)
                        outp[(size_t)(b0 + bb) * (3 * CIN_S) + n] = v;   // direct
                    else
                        outp[((size_t)jh * CIN_B + b0 + bb) * CIN_S + n] = v;
                }
            }
        }
    }
}

// combine jh-partials of layer2's H: H2c[b][d][n<208] = p0[b][n][d]+p1[b][n][d]
__global__ __launch_bounds__(256) void cin_comb(const unsigned short* __restrict__ Hacc,
                                                unsigned short* __restrict__ H2c) {
    __shared__ unsigned short T[208][33];
    const int b = blockIdx.x;
    const unsigned short* p0 = Hacc + (size_t)b * 208 * CIN_D;
    const unsigned short* p1 = p0 + (size_t)CIN_B * 208 * CIN_D;
    for (int e = threadIdx.x; e < 208 * CIN_D; e += 256) {
        T[e >> 5][e & 31] = f2h(h2f(p0[e]) + h2f(p1[e]));
    }
    __syncthreads();
    const int d = threadIdx.x >> 3, c = threadIdx.x & 7;   // 32 d x 8 chunks of 26
    unsigned short* dst = H2c + ((size_t)b * CIN_D + d) * 208 + c * 26;
#pragma unroll
    for (int q = 0; q < 26; ++q) dst[q] = T[c * 26 + q][d];
}

// out[b, 200+t] from jh-partial sums (t in [0,400))
__global__ __launch_bounds__(256) void cin_outc(const float* __restrict__ p2,
                                                const float* __restrict__ p3,
                                                float* __restrict__ out) {
    int e = blockIdx.x * 256 + threadIdx.x;   // 512*400 exact
    int b = e / 400, t = e - b * 400;
    int half = t / 200, n = t - half * 200;
    const float* p = half ? p3 : p2;
    out[(size_t)b * 600 + 200 + half * 200 + n] =
        p[(size_t)b * CIN_S + n] + p[(size_t)(CIN_B + b) * CIN_S + n];
}

extern "C" void kernel_launch(void* const* d_in, const int* in_sizes, int n_in,
                              void* d_out, int out_size, void* d_ws, size_t ws_size,
                              hipStream_t stream) {
    const float* X  = (const float*)d_in[0];
    const float* W0 = (const float*)d_in[1];
    const float* W1 = (const float*)d_in[2];
    const float* W2 = (const float*)d_in[3];
    float* out = (float*)d_out;

    unsigned short* Wtk1 = (unsigned short*)d_ws;             // 120*4096
    unsigned short* Wtk2 = Wtk1 + (size_t)120 * 4096;         // 520*4096 each
    unsigned short* Wtk3 = Wtk2 + (size_t)520 * 4096;
    unsigned short* X0hd = Wtk3 + (size_t)520 * 4096;         // 512*32*48
    unsigned short* Xh   = X0hd + (size_t)CIN_B * CIN_D * 48; // 512*40*32
    unsigned short* H1   = Xh + (size_t)CIN_B * CIN_F0 * CIN_D; // 512*32*224
    unsigned short* Hacc = H1 + (size_t)CIN_B * CIN_D * 224;  // 2*512*208*32 f16
    unsigned short* H2c  = Hacc + (size_t)2 * CIN_B * 208 * CIN_D; // 512*32*208
    float* outp2 = (float*)(H2c + (size_t)CIN_B * CIN_D * 208);    // 2*512*200
    float* outp3 = outp2 + (size_t)2 * CIN_B * CIN_S;
    // total ws ~47 MB

    prep_w<CIN_F0, 3><<<120, 256, 0, stream>>>(W0, Wtk1);
    prep_w2<<<1040, 256, 0, stream>>>(W1, Wtk2, W2, Wtk3);
    prep_x<<<(CIN_B * CIN_F0 * CIN_D) / 256, 256, 0, stream>>>(X, X0hd, Xh);

    cin_layer<3, 3, 48, 1><<<dim3(CIN_B / 2, 1), 448, 0, stream>>>(X0hd, Xh, Wtk1, H1, out);
    cin_layer<7, 13, 224, 2><<<dim3(CIN_B / 2, 2), 448, 0, stream>>>(H1, Xh, Wtk2, Hacc, outp2);
    cin_comb<<<CIN_B, 256, 0, stream>>>(Hacc, H2c);
    cin_layer<7, 13, 208, 3><<<dim3(CIN_B / 2, 2), 448, 0, stream>>>(H2c, Xh, Wtk3, nullptr, outp3);

    cin_outc<<<(CIN_B * 400) / 256, 256, 0, stream>>>(outp2, outp3, out);
}